// Round 4
// baseline (525.705 us; speedup 1.0000x reference)
//
#include <hip/hip_runtime.h>
#include <stdint.h>

#define BATCH  65536
#define IN_DIM 1024
#define MASKED 512
#define HIDDEN 1024

typedef unsigned short u16;
typedef __bf16 bf16x8 __attribute__((ext_vector_type(8)));
typedef float  f32x4  __attribute__((ext_vector_type(4)));

typedef __attribute__((address_space(1))) void gvoid;
typedef __attribute__((address_space(3))) void lvoid;

#define WAITV(N) asm volatile("s_waitcnt vmcnt(" #N ")" ::: "memory")
#define WAITL0() asm volatile("s_waitcnt lgkmcnt(0)" ::: "memory")
#define FENCE()  asm volatile("" ::: "memory")

__device__ __forceinline__ u16 f32_to_bf16(float f) {
    union { float f; uint32_t u; } v; v.f = f;
    uint32_t r = v.u + 0x7FFFu + ((v.u >> 16) & 1u);   // round-to-nearest-even
    return (u16)(r >> 16);
}

// ---------------------------------------------------------------------------
// prep: x (BATCH x IN_DIM f32) -> xm (BATCH x MASKED bf16)  [even columns]
// ---------------------------------------------------------------------------
__global__ void prep_xm(const float* __restrict__ x, u16* __restrict__ xm) {
    int idx = blockIdx.x * blockDim.x + threadIdx.x;   // 0 .. BATCH*IN_DIM/8
    const float4* xv = reinterpret_cast<const float4*>(x);
    float4 v0 = xv[idx * 2];
    float4 v1 = xv[idx * 2 + 1];
    ushort4 o;
    o.x = f32_to_bf16(v0.x);
    o.y = f32_to_bf16(v0.z);
    o.z = f32_to_bf16(v1.x);
    o.w = f32_to_bf16(v1.z);
    reinterpret_cast<ushort4*>(xm)[idx] = o;
}

// ---------------------------------------------------------------------------
// weight convert+transpose: W (K x N f32, row-major) -> Wt (N x K bf16)
// ---------------------------------------------------------------------------
__global__ void wconv(const float* __restrict__ W, u16* __restrict__ Wt,
                      int K, int N) {
    __shared__ float t[32][33];
    const int nbk = K / 32;
    const int bk = blockIdx.x % nbk;
    const int bn = blockIdx.x / nbk;
    const int tx = threadIdx.x & 31;
    const int ty = threadIdx.x >> 5;   // 0..7
    const int k0 = bk * 32, n0 = bn * 32;
    #pragma unroll
    for (int i = 0; i < 4; ++i)
        t[ty + i * 8][tx] = W[(int64_t)(k0 + ty + i * 8) * N + n0 + tx];
    __syncthreads();
    #pragma unroll
    for (int i = 0; i < 4; ++i)
        Wt[(int64_t)(n0 + ty + i * 8) * K + k0 + tx] = f32_to_bf16(t[tx][ty + i * 8]);
}

// ---------------------------------------------------------------------------
// Deep-pipelined GEMM: C(MxN) = A(MxK,bf16) @ Bt(NxK,bf16)^T + bias
// MODE 0: C = relu(.) -> bf16 Cb
// MODE 1: coupling epilogue: y[m][2n] = x[m][2n]; y[m][2n+1] = x[m][2n+1] + t
//
// 256x256 tile, 512 threads = 8 waves (2 M-waves x 4 N-waves), per-wave output
// 128x64 via 8x4 16x16x32 fragments. LDS: 4-slot ring (BK=32 each):
//   compute slot kt while staging slot kt+3 -> 3 K-tiles in flight,
//   counted vmcnt(8) boundaries (never 0 in steady state)  [T3+T4]
// BK=32 => LDS rows are 64B, so fragment-read bank-group = (row%2)*4+(lane>>4)
// which is uniform over all 8 bank groups: conflict-free without swizzle.
// s_setprio around MFMA clusters [T5]. 1 block/CU (128KB LDS), ~220 VGPR.
// ---------------------------------------------------------------------------
template<int K, int N, int MODE>
__global__ __launch_bounds__(512, 2)
void gemm256(const u16* __restrict__ A, const u16* __restrict__ Bt,
             const float* __restrict__ bias,
             u16* __restrict__ Cb,
             const float* __restrict__ X,
             float* __restrict__ Y) {
    constexpr int BK = 32;
    constexpr int NT = K / BK;
    __shared__ __align__(16) u16 As[4][256 * BK];
    __shared__ __align__(16) u16 Bs[4][256 * BK];

    const int tid  = threadIdx.x;
    const int lane = tid & 63;
    const int w    = tid >> 6;      // wave 0..7
    const int wm   = w >> 2;        // 0..1  (M half)
    const int wn   = w & 3;         // 0..3  (N quarter)

    // T1: XCD swizzle (all grids are multiples of 8 -> bijective)
    const int nwg = gridDim.x;
    const int cpx = nwg >> 3;
    const int bid = (blockIdx.x & 7) * cpx + (blockIdx.x >> 3);
    constexpr int nbn = N / 256;
    const int m0 = (bid / nbn) * 256;
    const int n0 = (bid % nbn) * 256;

    // staging geometry: one slot = 256 rows x 32 k x 2B = 16KB = 1024 chunks
    // of 16B. chunk c: row = c>>2, kslot = (c&3)*8.  Wave w covers chunks
    // [w*64, w*64+64) (instr 1, rows w*16..+16) and +512 (instr 2, rows +128).
    const int srow = w * 16 + (lane >> 2);
    const int sg   = (lane & 3) * 8;
    const u16* aS = A  + (int64_t)(m0 + srow) * K + sg;
    const u16* bS = Bt + (int64_t)(n0 + srow) * K + sg;
    const int lOff = w * 512;   // LDS element offset of this wave's chunk run

#define STG_A1(kt) __builtin_amdgcn_global_load_lds((gvoid*)(aS + (kt)*BK),          (lvoid*)(&As[(kt)&3][lOff]),        16, 0, 0)
#define STG_A2(kt) __builtin_amdgcn_global_load_lds((gvoid*)(aS + 128*K + (kt)*BK),  (lvoid*)(&As[(kt)&3][4096 + lOff]), 16, 0, 0)
#define STG_B1(kt) __builtin_amdgcn_global_load_lds((gvoid*)(bS + (kt)*BK),          (lvoid*)(&Bs[(kt)&3][lOff]),        16, 0, 0)
#define STG_B2(kt) __builtin_amdgcn_global_load_lds((gvoid*)(bS + 128*K + (kt)*BK),  (lvoid*)(&Bs[(kt)&3][4096 + lOff]), 16, 0, 0)

    f32x4 acc[8][4];
    #pragma unroll
    for (int i = 0; i < 8; ++i)
        #pragma unroll
        for (int j = 0; j < 4; ++j)
            acc[i][j] = f32x4{0.f, 0.f, 0.f, 0.f};

    // prologue: stage slots 0,1,2 (12 loads), drain slot 0 (oldest 4)
    STG_A1(0); STG_A2(0); STG_B1(0); STG_B2(0);
    STG_A1(1); STG_A2(1); STG_B1(1); STG_B2(1);
    STG_A1(2); STG_A2(2); STG_B1(2); STG_B2(2);
    WAITV(8);
    __builtin_amdgcn_s_barrier();
    FENCE();

    const int arow = wm * 128 + (lane & 15);   // + mf*16 (+64 in phase 2)
    const int brow = wn * 64  + (lane & 15);   // + nf*16
    const int kcol = (lane >> 4) * 8;

    for (int kt = 0; kt < NT; ++kt) {
        const int s = kt & 3;
        const u16* Asl = As[s];
        const u16* Bsl = Bs[s];
        bf16x8 a[4], b[4];

        // ---- phase 1: M-frags 0-3 x N-frags 0-3 ----
        #pragma unroll
        for (int mf = 0; mf < 4; ++mf)
            a[mf] = *reinterpret_cast<const bf16x8*>(&Asl[(arow + mf * 16) * BK + kcol]);
        #pragma unroll
        for (int nf = 0; nf < 4; ++nf)
            b[nf] = *reinterpret_cast<const bf16x8*>(&Bsl[(brow + nf * 16) * BK + kcol]);
        if (kt + 3 < NT) { STG_A1(kt + 3); STG_B1(kt + 3); }
        __builtin_amdgcn_s_setprio(1);
        #pragma unroll
        for (int mf = 0; mf < 4; ++mf)
            #pragma unroll
            for (int nf = 0; nf < 4; ++nf)
                acc[mf][nf] = __builtin_amdgcn_mfma_f32_16x16x32_bf16(
                    a[mf], b[nf], acc[mf][nf], 0, 0, 0);
        __builtin_amdgcn_s_setprio(0);
        __builtin_amdgcn_s_barrier();
        FENCE();

        // ---- phase 2: M-frags 4-7, b reused ----
        bf16x8 a2[4];
        #pragma unroll
        for (int mf = 0; mf < 4; ++mf)
            a2[mf] = *reinterpret_cast<const bf16x8*>(&Asl[(arow + 64 + mf * 16) * BK + kcol]);
        if (kt + 3 < NT) { STG_A2(kt + 3); STG_B2(kt + 3); }
        __builtin_amdgcn_s_setprio(1);
        #pragma unroll
        for (int mf = 0; mf < 4; ++mf)
            #pragma unroll
            for (int nf = 0; nf < 4; ++nf)
                acc[mf + 4][nf] = __builtin_amdgcn_mfma_f32_16x16x32_bf16(
                    a2[mf], b[nf], acc[mf + 4][nf], 0, 0, 0);
        __builtin_amdgcn_s_setprio(0);

        // boundary: all LDS reads of this slot retired before anyone can
        // overwrite it next window (rule #18: lgkm drain + sched fence),
        // then counted vmcnt so next slot's DMA is landed. Never 0 mid-loop.
        WAITL0();
        __builtin_amdgcn_sched_barrier(0);
        if (kt < NT - 3)       { WAITV(8); }
        else if (kt == NT - 3) { WAITV(4); }
        else if (kt == NT - 2) { WAITV(0); }
        if (kt < NT - 1) {
            __builtin_amdgcn_s_barrier();
            FENCE();
        }
    }

    // epilogue. C/D layout (m89-verified): col = lane&15, row = (lane>>4)*4+reg
    const int cl = lane & 15;
    const int rg = (lane >> 4) * 4;
    #pragma unroll
    for (int nf = 0; nf < 4; ++nf) {
        const int n  = n0 + wn * 64 + nf * 16 + cl;
        const float bv = bias[n];
        #pragma unroll
        for (int mf = 0; mf < 8; ++mf) {
            #pragma unroll
            for (int r = 0; r < 4; ++r) {
                const int m = m0 + wm * 128 + mf * 16 + rg + r;
                float v = acc[mf][nf][r] + bv;
                if (MODE == 0) {
                    v = v > 0.f ? v : 0.f;
                    Cb[(int64_t)m * N + n] = f32_to_bf16(v);
                } else {
                    const int64_t p = (int64_t)m * IN_DIM + 2 * n;
                    float2 xv = *reinterpret_cast<const float2*>(&X[p]);
                    float2 o;
                    o.x = xv.x;          // even column: exact copy
                    o.y = xv.y + v;      // odd column: x + translation
                    *reinterpret_cast<float2*>(&Y[p]) = o;
                }
            }
        }
    }
#undef STG_A1
#undef STG_A2
#undef STG_B1
#undef STG_B2
}

// ---------------------------------------------------------------------------
extern "C" void kernel_launch(void* const* d_in, const int* in_sizes, int n_in,
                              void* d_out, int out_size, void* d_ws, size_t ws_size,
                              hipStream_t stream) {
    const float* x  = (const float*)d_in[0];
    const float* W1 = (const float*)d_in[1];
    const float* b1 = (const float*)d_in[2];
    const float* W2 = (const float*)d_in[3];
    const float* b2 = (const float*)d_in[4];
    const float* W3 = (const float*)d_in[5];
    const float* b3 = (const float*)d_in[6];
    float* y = (float*)d_out;

    char* ws = (char*)d_ws;
    // layout: h1 (128MB) | h2 (128MB, first 64MB aliased by xm) | W1t|W2t|W3t
    u16* h1  = (u16*)(ws);
    u16* h2  = (u16*)(ws + 134217728);
    u16* xm  = (u16*)(ws + 134217728);                 // dead before h2 is written
    u16* W1t = (u16*)(ws + 268435456);
    u16* W2t = (u16*)(ws + 268435456 + 1048576);
    u16* W3t = (u16*)(ws + 268435456 + 1048576 + 2097152);

    // 1) extract even columns -> bf16
    prep_xm<<<BATCH * IN_DIM / 8 / 256, 256, 0, stream>>>(x, xm);

    // 2) convert + transpose weights to bf16 N x K
    wconv<<<(MASKED / 32) * (HIDDEN / 32), 256, 0, stream>>>(W1, W1t, MASKED, HIDDEN);
    wconv<<<(HIDDEN / 32) * (HIDDEN / 32), 256, 0, stream>>>(W2, W2t, HIDDEN, HIDDEN);
    wconv<<<(HIDDEN / 32) * ((IN_DIM - MASKED) / 32), 256, 0, stream>>>(W3, W3t, HIDDEN, IN_DIM - MASKED);

    // 3) three deep-pipelined GEMMs (grids: 1024 / 1024 / 512 — all %8==0)
    gemm256<MASKED, HIDDEN, 0><<<(BATCH / 256) * (HIDDEN / 256), 512, 0, stream>>>(
        xm, W1t, b1, h1, nullptr, nullptr);
    gemm256<HIDDEN, HIDDEN, 0><<<(BATCH / 256) * (HIDDEN / 256), 512, 0, stream>>>(
        h1, W2t, b2, h2, nullptr, nullptr);
    gemm256<HIDDEN, IN_DIM - MASKED, 1><<<(BATCH / 256) * ((IN_DIM - MASKED) / 256), 512, 0, stream>>>(
        h2, W3t, b3, nullptr, x, y);
}

// Round 5
// 521.443 us; speedup vs baseline: 1.0082x; 1.0082x over previous
//
#include <hip/hip_runtime.h>
#include <stdint.h>

#define BATCH  65536
#define IN_DIM 1024
#define MASKED 512
#define HIDDEN 1024

typedef unsigned short u16;
typedef __bf16 bf16x8 __attribute__((ext_vector_type(8)));
typedef float  f32x4  __attribute__((ext_vector_type(4)));

typedef __attribute__((address_space(1))) void gvoid;
typedef __attribute__((address_space(3))) void lvoid;

#define WAITV(N) asm volatile("s_waitcnt vmcnt(" #N ")" ::: "memory")
#define WAITL0() asm volatile("s_waitcnt lgkmcnt(0)" ::: "memory")
#define FENCE()  asm volatile("" ::: "memory")

__device__ __forceinline__ u16 f32_to_bf16(float f) {
    union { float f; uint32_t u; } v; v.f = f;
    uint32_t r = v.u + 0x7FFFu + ((v.u >> 16) & 1u);   // round-to-nearest-even
    return (u16)(r >> 16);
}

// ---------------------------------------------------------------------------
// prep: x (BATCH x IN_DIM f32) -> xm (BATCH x MASKED bf16)  [even columns]
// ---------------------------------------------------------------------------
__global__ void prep_xm(const float* __restrict__ x, u16* __restrict__ xm) {
    int idx = blockIdx.x * blockDim.x + threadIdx.x;   // 0 .. BATCH*IN_DIM/8
    const float4* xv = reinterpret_cast<const float4*>(x);
    float4 v0 = xv[idx * 2];
    float4 v1 = xv[idx * 2 + 1];
    ushort4 o;
    o.x = f32_to_bf16(v0.x);
    o.y = f32_to_bf16(v0.z);
    o.z = f32_to_bf16(v1.x);
    o.w = f32_to_bf16(v1.z);
    reinterpret_cast<ushort4*>(xm)[idx] = o;
}

// ---------------------------------------------------------------------------
// weight convert+transpose: W (K x N f32, row-major) -> Wt (N x K bf16)
// ---------------------------------------------------------------------------
__global__ void wconv(const float* __restrict__ W, u16* __restrict__ Wt,
                      int K, int N) {
    __shared__ float t[32][33];
    const int nbk = K / 32;
    const int bk = blockIdx.x % nbk;
    const int bn = blockIdx.x / nbk;
    const int tx = threadIdx.x & 31;
    const int ty = threadIdx.x >> 5;   // 0..7
    const int k0 = bk * 32, n0 = bn * 32;
    #pragma unroll
    for (int i = 0; i < 4; ++i)
        t[ty + i * 8][tx] = W[(int64_t)(k0 + ty + i * 8) * N + n0 + tx];
    __syncthreads();
    #pragma unroll
    for (int i = 0; i < 4; ++i)
        Wt[(int64_t)(n0 + ty + i * 8) * K + k0 + tx] = f32_to_bf16(t[tx][ty + i * 8]);
}

// ---------------------------------------------------------------------------
// Deep-pipelined GEMM: C(MxN) = A(MxK,bf16) @ Bt(NxK,bf16)^T + bias
// MODE 0: C = relu(.) -> bf16 Cb
// MODE 1: coupling epilogue: y[m][2n] = x[m][2n]; y[m][2n+1] = x[m][2n+1] + t
//
// 256x256 tile, 512 threads = 8 waves (2 M-waves x 4 N-waves), per-wave output
// 128x64 via 8x4 16x16x32 fragments. LDS: 4-slot ring (BK=32 each):
//   compute slot kt while staging slot kt+3 -> 3 K-tiles in flight,
//   counted vmcnt(8) boundaries (never 0 in steady state)  [T3+T4]
//
// T2 k-slot swizzle (both-sides, rule #21): LDS chunk (row,q) holds global
// (row, q ^ ((row>>1)&3)).  Write side: global_load_lds writes linearly, so
// the permutation is applied on the per-lane GLOBAL source address (stays
// inside one 64B line -> coalescing preserved).  Read side: kcol is XOR'd
// with the same mask.  Result: each 16-lane quarter of a ds_read_b128
// spreads over all 8 four-bank groups x2 = 2-way = free (m136).  Without
// this, all 16 lanes hit 2 groups = 8-way conflict (R3: 1.26e7 conflicts).
// ---------------------------------------------------------------------------
template<int K, int N, int MODE>
__global__ __launch_bounds__(512, 2)
void gemm256(const u16* __restrict__ A, const u16* __restrict__ Bt,
             const float* __restrict__ bias,
             u16* __restrict__ Cb,
             const float* __restrict__ X,
             float* __restrict__ Y) {
    constexpr int BK = 32;
    constexpr int NT = K / BK;
    __shared__ __align__(16) u16 As[4][256 * BK];
    __shared__ __align__(16) u16 Bs[4][256 * BK];

    const int tid  = threadIdx.x;
    const int lane = tid & 63;
    const int w    = tid >> 6;      // wave 0..7
    const int wm   = w >> 2;        // 0..1  (M half)
    const int wn   = w & 3;         // 0..3  (N quarter)

    // T1: XCD swizzle (all grids are multiples of 8 -> bijective)
    const int nwg = gridDim.x;
    const int cpx = nwg >> 3;
    const int bid = (blockIdx.x & 7) * cpx + (blockIdx.x >> 3);
    constexpr int nbn = N / 256;
    const int m0 = (bid / nbn) * 256;
    const int n0 = (bid % nbn) * 256;

    // staging geometry: one slot = 256 rows x 32 k x 2B = 16KB = 1024 chunks
    // of 16B. chunk c: row = c>>2, q = c&3.  Wave w covers chunks
    // [w*64, w*64+64) (instr 1, rows w*16..+16) and +512 (instr 2, rows +128).
    // T2: global source k-slot q' = q ^ ((row>>1)&3) = (lane&3)^((lane>>3)&3).
    const int srow = w * 16 + (lane >> 2);
    const int sg   = ((lane & 3) ^ ((lane >> 3) & 3)) * 8;
    const u16* aS = A  + (int64_t)(m0 + srow) * K + sg;
    const u16* bS = Bt + (int64_t)(n0 + srow) * K + sg;
    const int lOff = w * 512;   // LDS element offset of this wave's chunk run

#define STG_A1(kt) __builtin_amdgcn_global_load_lds((gvoid*)(aS + (kt)*BK),          (lvoid*)(&As[(kt)&3][lOff]),        16, 0, 0)
#define STG_A2(kt) __builtin_amdgcn_global_load_lds((gvoid*)(aS + 128*K + (kt)*BK),  (lvoid*)(&As[(kt)&3][4096 + lOff]), 16, 0, 0)
#define STG_B1(kt) __builtin_amdgcn_global_load_lds((gvoid*)(bS + (kt)*BK),          (lvoid*)(&Bs[(kt)&3][lOff]),        16, 0, 0)
#define STG_B2(kt) __builtin_amdgcn_global_load_lds((gvoid*)(bS + 128*K + (kt)*BK),  (lvoid*)(&Bs[(kt)&3][4096 + lOff]), 16, 0, 0)

    f32x4 acc[8][4];
    #pragma unroll
    for (int i = 0; i < 8; ++i)
        #pragma unroll
        for (int j = 0; j < 4; ++j)
            acc[i][j] = f32x4{0.f, 0.f, 0.f, 0.f};

    // prologue: stage slots 0,1,2 (12 loads), drain slot 0 (oldest 4)
    STG_A1(0); STG_A2(0); STG_B1(0); STG_B2(0);
    STG_A1(1); STG_A2(1); STG_B1(1); STG_B2(1);
    STG_A1(2); STG_A2(2); STG_B1(2); STG_B2(2);
    WAITV(8);
    __builtin_amdgcn_s_barrier();
    FENCE();

    const int arow = wm * 128 + (lane & 15);   // + mf*16 (+64 in phase 2)
    const int brow = wn * 64  + (lane & 15);   // + nf*16
    // T2 read side: q_lds = q_read ^ ((row>>1)&3); all row-base terms are
    // multiples of 16, so the mask = ((lane&15)>>1)&3 — one constant per lane.
    const int kcol = ((lane >> 4) ^ (((lane & 15) >> 1) & 3)) * 8;

    for (int kt = 0; kt < NT; ++kt) {
        const int s = kt & 3;
        const u16* Asl = As[s];
        const u16* Bsl = Bs[s];
        bf16x8 a[4], b[4];

        // ---- phase 1: M-frags 0-3 x N-frags 0-3 ----
        #pragma unroll
        for (int mf = 0; mf < 4; ++mf)
            a[mf] = *reinterpret_cast<const bf16x8*>(&Asl[(arow + mf * 16) * BK + kcol]);
        #pragma unroll
        for (int nf = 0; nf < 4; ++nf)
            b[nf] = *reinterpret_cast<const bf16x8*>(&Bsl[(brow + nf * 16) * BK + kcol]);
        if (kt + 3 < NT) { STG_A1(kt + 3); STG_B1(kt + 3); }
        __builtin_amdgcn_s_setprio(1);
        #pragma unroll
        for (int mf = 0; mf < 4; ++mf)
            #pragma unroll
            for (int nf = 0; nf < 4; ++nf)
                acc[mf][nf] = __builtin_amdgcn_mfma_f32_16x16x32_bf16(
                    a[mf], b[nf], acc[mf][nf], 0, 0, 0);
        __builtin_amdgcn_s_setprio(0);
        __builtin_amdgcn_s_barrier();
        FENCE();

        // ---- phase 2: M-frags 4-7, b reused ----
        bf16x8 a2[4];
        #pragma unroll
        for (int mf = 0; mf < 4; ++mf)
            a2[mf] = *reinterpret_cast<const bf16x8*>(&Asl[(arow + 64 + mf * 16) * BK + kcol]);
        if (kt + 3 < NT) { STG_A2(kt + 3); STG_B2(kt + 3); }
        __builtin_amdgcn_s_setprio(1);
        #pragma unroll
        for (int mf = 0; mf < 4; ++mf)
            #pragma unroll
            for (int nf = 0; nf < 4; ++nf)
                acc[mf + 4][nf] = __builtin_amdgcn_mfma_f32_16x16x32_bf16(
                    a2[mf], b[nf], acc[mf + 4][nf], 0, 0, 0);
        __builtin_amdgcn_s_setprio(0);

        // boundary: all LDS reads of this slot retired before anyone can
        // overwrite it next window (rule #18: lgkm drain + sched fence),
        // then counted vmcnt so next slot's DMA is landed. Never 0 mid-loop.
        WAITL0();
        __builtin_amdgcn_sched_barrier(0);
        if (kt < NT - 3)       { WAITV(8); }
        else if (kt == NT - 3) { WAITV(4); }
        else if (kt == NT - 2) { WAITV(0); }
        if (kt < NT - 1) {
            __builtin_amdgcn_s_barrier();
            FENCE();
        }
    }

    // epilogue. C/D layout (m89-verified): col = lane&15, row = (lane>>4)*4+reg
    const int cl = lane & 15;
    const int rg = (lane >> 4) * 4;
    #pragma unroll
    for (int nf = 0; nf < 4; ++nf) {
        const int n  = n0 + wn * 64 + nf * 16 + cl;
        const float bv = bias[n];
        #pragma unroll
        for (int mf = 0; mf < 8; ++mf) {
            #pragma unroll
            for (int r = 0; r < 4; ++r) {
                const int m = m0 + wm * 128 + mf * 16 + rg + r;
                float v = acc[mf][nf][r] + bv;
                if (MODE == 0) {
                    v = v > 0.f ? v : 0.f;
                    Cb[(int64_t)m * N + n] = f32_to_bf16(v);
                } else {
                    const int64_t p = (int64_t)m * IN_DIM + 2 * n;
                    float2 xv = *reinterpret_cast<const float2*>(&X[p]);
                    float2 o;
                    o.x = xv.x;          // even column: exact copy
                    o.y = xv.y + v;      // odd column: x + translation
                    *reinterpret_cast<float2*>(&Y[p]) = o;
                }
            }
        }
    }
#undef STG_A1
#undef STG_A2
#undef STG_B1
#undef STG_B2
}

// ---------------------------------------------------------------------------
extern "C" void kernel_launch(void* const* d_in, const int* in_sizes, int n_in,
                              void* d_out, int out_size, void* d_ws, size_t ws_size,
                              hipStream_t stream) {
    const float* x  = (const float*)d_in[0];
    const float* W1 = (const float*)d_in[1];
    const float* b1 = (const float*)d_in[2];
    const float* W2 = (const float*)d_in[3];
    const float* b2 = (const float*)d_in[4];
    const float* W3 = (const float*)d_in[5];
    const float* b3 = (const float*)d_in[6];
    float* y = (float*)d_out;

    char* ws = (char*)d_ws;
    // layout: h1 (128MB) | h2 (128MB, first 64MB aliased by xm) | W1t|W2t|W3t
    u16* h1  = (u16*)(ws);
    u16* h2  = (u16*)(ws + 134217728);
    u16* xm  = (u16*)(ws + 134217728);                 // dead before h2 is written
    u16* W1t = (u16*)(ws + 268435456);
    u16* W2t = (u16*)(ws + 268435456 + 1048576);
    u16* W3t = (u16*)(ws + 268435456 + 1048576 + 2097152);

    // 1) extract even columns -> bf16
    prep_xm<<<BATCH * IN_DIM / 8 / 256, 256, 0, stream>>>(x, xm);

    // 2) convert + transpose weights to bf16 N x K
    wconv<<<(MASKED / 32) * (HIDDEN / 32), 256, 0, stream>>>(W1, W1t, MASKED, HIDDEN);
    wconv<<<(HIDDEN / 32) * (HIDDEN / 32), 256, 0, stream>>>(W2, W2t, HIDDEN, HIDDEN);
    wconv<<<(HIDDEN / 32) * ((IN_DIM - MASKED) / 32), 256, 0, stream>>>(W3, W3t, HIDDEN, IN_DIM - MASKED);

    // 3) three deep-pipelined GEMMs (grids: 1024 / 1024 / 512 — all %8==0)
    gemm256<MASKED, HIDDEN, 0><<<(BATCH / 256) * (HIDDEN / 256), 512, 0, stream>>>(
        xm, W1t, b1, h1, nullptr, nullptr);
    gemm256<HIDDEN, HIDDEN, 0><<<(BATCH / 256) * (HIDDEN / 256), 512, 0, stream>>>(
        h1, W2t, b2, h2, nullptr, nullptr);
    gemm256<HIDDEN, IN_DIM - MASKED, 1><<<(BATCH / 256) * ((IN_DIM - MASKED) / 256), 512, 0, stream>>>(
        h2, W3t, b3, nullptr, x, y);
}